// Round 1
// baseline (1278.732 us; speedup 1.0000x reference)
//
#include <hip/hip_runtime.h>
#include <cstdint>

typedef short bf8 __attribute__((ext_vector_type(8)));   // 8 x bf16 (bit pattern)
typedef float f4  __attribute__((ext_vector_type(4)));
typedef uint32_t u32x4 __attribute__((ext_vector_type(4)));
typedef unsigned short u16;

__device__ __forceinline__ u16 f2bf(float f) {
  union { float f; uint32_t u; } v; v.f = f;
  uint32_t u = v.u + 0x7fffu + ((v.u >> 16) & 1u);   // RNE
  return (u16)(u >> 16);
}

__device__ __forceinline__ uint32_t pk2(float lo, float hi) {
  return (uint32_t)f2bf(lo) | ((uint32_t)f2bf(hi) << 16);
}

// load 8 consecutive f32 (16B-aligned) and convert to a bf16x8 MFMA fragment
__device__ __forceinline__ bf8 ld_cvt8(const float* p) {
  f4 a = *(const f4*)p;
  f4 b = *(const f4*)(p + 4);
  u32x4 r;
  r[0] = pk2(a[0], a[1]);
  r[1] = pk2(a[2], a[3]);
  r[2] = pk2(b[0], b[1]);
  r[3] = pk2(b[2], b[3]);
  return __builtin_bit_cast(bf8, r);
}

template<bool WB>
__device__ __forceinline__ bf8 ldW(const void* p, size_t off) {
  if constexpr (WB) return *(const bf8*)((const u16*)p + off);
  else              return ld_cvt8((const float*)p + off);
}

// activation fragment load: bf16 from workspace (XB) or f32+convert
template<bool XB>
__device__ __forceinline__ bf8 ldA(const float* xf, const u16* xb, size_t off) {
  if constexpr (XB) return *(const bf8*)(xb + off);
  else              return ld_cvt8(xf + off);
}

#define MFMA(a, b, c) __builtin_amdgcn_mfma_f32_16x16x32_bf16((a), (b), (c), 0, 0, 0)

// Problem constants: 1024 groups of (seq=128, C=256), 8 heads of e=32.
constexpr int SEQ = 128;
constexpr int CH  = 256;
constexpr int NH  = 8;

// workspace layout (u16 elems): Wq @0 | Wkv @65536 | Wout @196608 | Wsc @262144 |
// Wsh @327680 | xb @393216 (33554432) | cb @33947648 (33554432)
constexpr size_t W_ELEMS = 393216;
constexpr size_t X_ELEMS = 33554432ull;   // 1024 * 128 * 256

// ---- prepass A: weights only (fallback when ws is small) ----
__global__ void cvt_weights(const float* __restrict__ wq, const float* __restrict__ wkv,
                            const float* __restrict__ wout, const float* __restrict__ wsc,
                            const float* __restrict__ wsh, u16* __restrict__ dst) {
  int i = (blockIdx.x * 256 + threadIdx.x) * 8;   // 0 .. 393208
  const float* s; int off;
  if      (i <  65536) { s = wq;   off = i; }
  else if (i < 196608) { s = wkv;  off = i -  65536; }
  else if (i < 262144) { s = wout; off = i - 196608; }
  else if (i < 327680) { s = wsc;  off = i - 262144; }
  else                 { s = wsh;  off = i - 327680; }
  *(bf8*)(dst + i) = ld_cvt8(s + off);
}

// ---- prepass B: weights + x + ctx -> bf16 workspace ----
__global__ void cvt_all(const float* __restrict__ wq, const float* __restrict__ wkv,
                        const float* __restrict__ wout, const float* __restrict__ wsc,
                        const float* __restrict__ wsh, const float* __restrict__ x,
                        const float* __restrict__ ctx, u16* __restrict__ dst) {
  const long nchunk = (long)((W_ELEMS + 2 * X_ELEMS) / 8);
  for (long c = blockIdx.x * (long)blockDim.x + threadIdx.x; c < nchunk;
       c += (long)gridDim.x * blockDim.x) {
    long i = c * 8;
    const float* s; long off;
    if      (i <  65536)  { s = wq;   off = i; }
    else if (i < 196608)  { s = wkv;  off = i -  65536; }
    else if (i < 262144)  { s = wout; off = i - 196608; }
    else if (i < 327680)  { s = wsc;  off = i - 262144; }
    else if (i < 393216)  { s = wsh;  off = i - 327680; }
    else if (i < (long)(W_ELEMS + X_ELEMS)) { s = x;   off = i - (long)W_ELEMS; }
    else                                    { s = ctx; off = i - (long)(W_ELEMS + X_ELEMS); }
    *(bf8*)(dst + i) = ld_cvt8(s + off);
  }
}

template<bool WB, bool XB>
__global__ __launch_bounds__(256, 2)
void fused_axattn(const float* __restrict__ x,   const float* __restrict__ ctx,
                  const u16* __restrict__ xb,    const u16* __restrict__ cb,
                  const void* __restrict__ Wq,  const void* __restrict__ Wkv,
                  const void* __restrict__ Wout,const void* __restrict__ Wsc,
                  const void* __restrict__ Wsh, float* __restrict__ out)
{
  __shared__ u16 sQ[SEQ][40];    // Qm, row-major, head-local 32 cols (wave-local rows)
  __shared__ u16 sK[SEQ][40];    // Km (cross-wave)
  __shared__ u16 sVT[32][136];   // Vm transposed: [d][j] (cross-wave)
  __shared__ u16 sP[SEQ][136];   // softmax probs, row-major (wave-local rows)
  __shared__ u16 sOh[SEQ][40];   // per-head attn output (wave-local rows)
  // total LDS = 10240+10240+8704+34816+10240 = 74240 B -> 2 blocks/CU

  const int tid  = threadIdx.x;
  const int wave = tid >> 6;
  const int lane = tid & 63;
  const int l15  = lane & 15;
  const int quad = lane >> 4;
  const int g    = blockIdx.x;
  const size_t gbase = (size_t)g * (SEQ * CH);
  const int ib = wave * 32;                  // this wave's 32 rows

  const float SCALE = 0.17677669529663687f;  // 1/sqrt(32)

  auto wrow = [&](const void* base, size_t row) -> const void* {
    if constexpr (WB) return (const void*)((const u16*)base + row * CH);
    else              return (const void*)((const float*)base + row * CH);
  };

  float rinv[2][4];                          // per-row 1/softmax-sum
  f4 pacc[2][16];                            // out-projection accumulators (live whole kernel)
  #pragma unroll
  for (int mt = 0; mt < 2; ++mt)
    #pragma unroll
    for (int nt = 0; nt < 16; ++nt) pacc[mt][nt] = 0.0f;

  for (int h = 0; h < NH; ++h) {
    // ===== Phase A: q,k,v,scale,shift as N=160 GEMM, one mt (16 rows) at a time ====
    // tiles: 0,1=q  2,3=k  4,5=v  6,7=scale  8,9=shift
    const int hn0 = h * 32 + l15;
    const void* bp[10];
    bp[0] = wrow(Wq,  hn0);        bp[1] = wrow(Wq,  hn0 + 16);
    bp[2] = wrow(Wkv, hn0);        bp[3] = wrow(Wkv, hn0 + 16);
    bp[4] = wrow(Wkv, hn0 + 256);  bp[5] = wrow(Wkv, hn0 + 272);
    bp[6] = wrow(Wsc, hn0);        bp[7] = wrow(Wsc, hn0 + 16);
    bp[8] = wrow(Wsh, hn0);        bp[9] = wrow(Wsh, hn0 + 16);

    #pragma unroll
    for (int mt = 0; mt < 2; ++mt) {
      f4 acc[10];
      #pragma unroll
      for (int t = 0; t < 10; ++t) acc[t] = 0.0f;

      const size_t arow = gbase + (size_t)(ib + 16 * mt + l15) * CH;
      #pragma unroll
      for (int kc = 0; kc < 8; ++kc) {
        const size_t cc = (size_t)kc * 32 + quad * 8;
        bf8 ax = ldA<XB>(x,   xb, arow + cc);
        bf8 ac = ldA<XB>(ctx, cb, arow + cc);
        #pragma unroll
        for (int t = 0; t < 10; ++t) {
          bf8 b = ldW<WB>(bp[t], cc);
          acc[t] = MFMA((t < 6) ? ax : ac, b, acc[t]);
        }
      }

      // FiLM modulation fully in-lane, write LDS
      #pragma unroll
      for (int r = 0; r < 4; ++r) {
        const int i = ib + 16 * mt + 4 * quad + r;
        const float sc0 = acc[6][r], sc1 = acc[7][r];
        const float sh0 = acc[8][r], sh1 = acc[9][r];
        sQ[i][l15]      = f2bf(sc0 * acc[0][r] + sh0);
        sQ[i][16 + l15] = f2bf(sc1 * acc[1][r] + sh1);
        sK[i][l15]      = f2bf(sc0 * acc[2][r] + sh0);
        sK[i][16 + l15] = f2bf(sc1 * acc[3][r] + sh1);
        sVT[l15][i]      = f2bf(sc0 * acc[4][r] + sh0);
        sVT[16 + l15][i] = f2bf(sc1 * acc[5][r] + sh1);
      }
    }
    __syncthreads();   // K,V from all waves visible

    // ===== S = Qm @ Km^T, softmax in registers (all wave-local LDS traffic) =====
    f4 sacc[2][8];
    #pragma unroll
    for (int mt = 0; mt < 2; ++mt) {
      const int i0 = ib + 16 * mt;
      bf8 a = *(const bf8*)(&sQ[i0 + l15][quad * 8]);
      #pragma unroll
      for (int ct = 0; ct < 8; ++ct) {
        bf8 b = *(const bf8*)(&sK[ct * 16 + l15][quad * 8]);
        f4 z = 0.0f;
        sacc[mt][ct] = MFMA(a, b, z);
      }
    }

    #pragma unroll
    for (int mt = 0; mt < 2; ++mt) {
      const int i0 = ib + 16 * mt;
      float mx[4] = {-3.4e38f, -3.4e38f, -3.4e38f, -3.4e38f};
      #pragma unroll
      for (int ct = 0; ct < 8; ++ct)
        #pragma unroll
        for (int r = 0; r < 4; ++r) mx[r] = fmaxf(mx[r], sacc[mt][ct][r]);
      #pragma unroll
      for (int m = 1; m <= 8; m <<= 1)
        #pragma unroll
        for (int r = 0; r < 4; ++r) mx[r] = fmaxf(mx[r], __shfl_xor(mx[r], m));

      float sm[4] = {0.f, 0.f, 0.f, 0.f};
      #pragma unroll
      for (int ct = 0; ct < 8; ++ct)
        #pragma unroll
        for (int r = 0; r < 4; ++r) {
          float p = __expf((sacc[mt][ct][r] - mx[r]) * SCALE);
          sm[r] += p;
          sP[i0 + 4 * quad + r][ct * 16 + l15] = f2bf(p);
        }
      #pragma unroll
      for (int m = 1; m <= 8; m <<= 1)
        #pragma unroll
        for (int r = 0; r < 4; ++r) sm[r] += __shfl_xor(sm[r], m);
      #pragma unroll
      for (int r = 0; r < 4; ++r) rinv[mt][r] = 1.0f / sm[r];
    }
    // sP write->read is wave-local; DS ops complete in order per wave.
    asm volatile("s_waitcnt lgkmcnt(0)" ::: "memory");

    // ===== O_h = P @ Vm (normalize at write), stage into sOh (wave-local) =====
    #pragma unroll
    for (int mt = 0; mt < 2; ++mt) {
      const int i0 = ib + 16 * mt;
      #pragma unroll
      for (int dt = 0; dt < 2; ++dt) {
        f4 o = 0.0f;
        #pragma unroll
        for (int kt = 0; kt < 4; ++kt) {
          bf8 a = *(const bf8*)(&sP[i0 + l15][kt * 32 + quad * 8]);
          bf8 b = *(const bf8*)(&sVT[dt * 16 + l15][kt * 32 + quad * 8]);
          o = MFMA(a, b, o);
        }
        #pragma unroll
        for (int r = 0; r < 4; ++r)
          sOh[i0 + 4 * quad + r][dt * 16 + l15] = f2bf(o[r] * rinv[mt][r]);
      }
    }
    asm volatile("s_waitcnt lgkmcnt(0)" ::: "memory");

    // ===== partial out-projection: pacc += O_h @ Wout[:, h*32 : h*32+32]^T =====
    {
      bf8 a0 = *(const bf8*)(&sOh[ib + l15][quad * 8]);
      bf8 a1 = *(const bf8*)(&sOh[ib + 16 + l15][quad * 8]);
      #pragma unroll
      for (int nt = 0; nt < 16; ++nt) {
        bf8 b = ldW<WB>(wrow(Wout, nt * 16 + l15), (size_t)h * 32 + quad * 8);
        pacc[0][nt] = MFMA(a0, b, pacc[0][nt]);
        pacc[1][nt] = MFMA(a1, b, pacc[1][nt]);
      }
    }
    __syncthreads();   // before next head overwrites sK/sVT
  }

  // ===== final store =====
  #pragma unroll
  for (int mt = 0; mt < 2; ++mt)
    #pragma unroll
    for (int nt = 0; nt < 16; ++nt)
      #pragma unroll
      for (int r = 0; r < 4; ++r)
        out[gbase + (size_t)(ib + 16 * mt + 4 * quad + r) * CH + nt * 16 + l15] =
            pacc[mt][nt][r];
}

extern "C" void kernel_launch(void* const* d_in, const int* in_sizes, int n_in,
                              void* d_out, int out_size, void* d_ws, size_t ws_size,
                              hipStream_t stream) {
  const float* x    = (const float*)d_in[0];
  const float* ctx  = (const float*)d_in[1];
  const float* Wq   = (const float*)d_in[2];
  const float* Wkv  = (const float*)d_in[3];
  const float* Wout = (const float*)d_in[4];
  const float* Wsc  = (const float*)d_in[5];
  const float* Wsh  = (const float*)d_in[6];
  float* o = (float*)d_out;

  const size_t need_full = (W_ELEMS + 2 * X_ELEMS) * sizeof(u16);   // 135,004,160 B

  if (ws_size >= need_full) {
    u16* w  = (u16*)d_ws;
    u16* xb = w + W_ELEMS;
    u16* cb = xb + X_ELEMS;
    cvt_all<<<dim3(8192), dim3(256), 0, stream>>>(Wq, Wkv, Wout, Wsc, Wsh, x, ctx, w);
    fused_axattn<true, true><<<dim3(1024), dim3(256), 0, stream>>>(
        x, ctx, xb, cb, w, w + 65536, w + 196608, w + 262144, w + 327680, o);
  } else if (ws_size >= W_ELEMS * sizeof(u16)) {
    u16* w = (u16*)d_ws;
    cvt_weights<<<dim3(192), dim3(256), 0, stream>>>(Wq, Wkv, Wout, Wsc, Wsh, w);
    fused_axattn<true, false><<<dim3(1024), dim3(256), 0, stream>>>(
        x, ctx, nullptr, nullptr, w, w + 65536, w + 196608, w + 262144, w + 327680, o);
  } else {
    fused_axattn<false, false><<<dim3(1024), dim3(256), 0, stream>>>(
        x, ctx, nullptr, nullptr, Wq, Wkv, Wout, Wsc, Wsh, o);
  }
}

// Round 2
// 1123.020 us; speedup vs baseline: 1.1387x; 1.1387x over previous
//
#include <hip/hip_runtime.h>
#include <cstdint>

typedef short bf8 __attribute__((ext_vector_type(8)));   // 8 x bf16 (bit pattern)
typedef float f4  __attribute__((ext_vector_type(4)));
typedef uint32_t u32x4 __attribute__((ext_vector_type(4)));
typedef unsigned short u16;

__device__ __forceinline__ u16 f2bf(float f) {
  union { float f; uint32_t u; } v; v.f = f;
  uint32_t u = v.u + 0x7fffu + ((v.u >> 16) & 1u);   // RNE
  return (u16)(u >> 16);
}

__device__ __forceinline__ uint32_t pk2(float lo, float hi) {
  return (uint32_t)f2bf(lo) | ((uint32_t)f2bf(hi) << 16);
}

// load 8 consecutive f32 (16B-aligned) and convert to a bf16x8 MFMA fragment
__device__ __forceinline__ bf8 ld_cvt8(const float* p) {
  f4 a = *(const f4*)p;
  f4 b = *(const f4*)(p + 4);
  u32x4 r;
  r[0] = pk2(a[0], a[1]);
  r[1] = pk2(a[2], a[3]);
  r[2] = pk2(b[0], b[1]);
  r[3] = pk2(b[2], b[3]);
  return __builtin_bit_cast(bf8, r);
}

#define MFMA(a, b, c) __builtin_amdgcn_mfma_f32_16x16x32_bf16((a), (b), (c), 0, 0, 0)

// Problem constants: 1024 groups of (seq=128, C=256), 8 heads of e=32.
constexpr int SEQ = 128;
constexpr int CH  = 256;
constexpr int NH  = 8;

// bf16 weight workspace layout (u16 elems)
constexpr size_t OQ   = 0;
constexpr size_t OKV  = 65536;
constexpr size_t OOUT = 196608;
constexpr size_t OSC  = 262144;
constexpr size_t OSH  = 327680;
constexpr size_t W_ELEMS  = 393216;
constexpr size_t OH_ELEMS = (size_t)1024 * SEQ * CH;   // 33,554,432

// weight-tile element offsets (WB path): q0,q1,k0,k1,v0,v1,sc0,sc1,sh0,sh1
__device__ constexpr size_t WOFF[10] = {
  OQ, OQ + 4096, OKV, OKV + 4096, OKV + 65536, OKV + 69632,
  OSC, OSC + 4096, OSH, OSH + 4096 };
__device__ constexpr int ROWADD[10] = {0, 16, 0, 16, 256, 272, 0, 16, 0, 16};

// ---- prepass: weights f32 -> bf16 workspace ----
__global__ void cvt_weights(const float* __restrict__ wq, const float* __restrict__ wkv,
                            const float* __restrict__ wout, const float* __restrict__ wsc,
                            const float* __restrict__ wsh, u16* __restrict__ dst) {
  int i = (blockIdx.x * 256 + threadIdx.x) * 8;   // 0 .. 393208
  const float* s; int off;
  if      (i <  65536) { s = wq;   off = i; }
  else if (i < 196608) { s = wkv;  off = i -  65536; }
  else if (i < 262144) { s = wout; off = i - 196608; }
  else if (i < 327680) { s = wsc;  off = i - 262144; }
  else                 { s = wsh;  off = i - 327680; }
  *(bf8*)(dst + i) = ld_cvt8(s + off);
}

template<bool WB, bool SPLIT>
__global__ __launch_bounds__(256, SPLIT ? 3 : 2)
void fused_axattn(const float* __restrict__ x,   const float* __restrict__ ctx,
                  const u16* __restrict__ Wb,
                  const float* __restrict__ Wqf, const float* __restrict__ Wkvf,
                  const float* __restrict__ Wscf, const float* __restrict__ Wshf,
                  const float* __restrict__ Woutf,
                  u16* __restrict__ Oh, float* __restrict__ out)
{
  __shared__ u16 sQ[SEQ][40];    // Qm, head-local 32 cols (wave-local rows)
  __shared__ u16 sK[SEQ][40];    // Km (cross-wave)
  __shared__ u16 sVT[32][136];   // Vm transposed: [d][j] (cross-wave)
  __shared__ u16 sP[SEQ][40];    // 32-key quarter of P (wave-local rows); also O staging (!SPLIT)
  // total LDS = 10240+10240+8704+10240 = 39424 B

  const int tid  = threadIdx.x;
  const int wave = tid >> 6;
  const int lane = tid & 63;
  const int l15  = lane & 15;
  const int quad = lane >> 4;
  const int g    = blockIdx.x;
  const size_t gbase = (size_t)g * (SEQ * CH);
  const int ib = wave * 32;                  // this wave's 32 rows

  const float SCALE = 0.17677669529663687f;  // 1/sqrt(32)
  const int vo = l15 * CH + quad * 8;        // shared per-lane weight offset (elems)

  f4 pacc[2][16];                            // only used when !SPLIT
  if constexpr (!SPLIT) {
    #pragma unroll
    for (int mt = 0; mt < 2; ++mt)
      #pragma unroll
      for (int nt = 0; nt < 16; ++nt) pacc[mt][nt] = 0.0f;
  }

  for (int h = 0; h < NH; ++h) {
    const int hoff = h * 32 * CH;            // 8192 elems per head of weight rows

    // B-fragment load for tile t at column cc (t is compile-time in unrolled loops)
    auto ldb = [&](int t, int cc) -> bf8 {
      if constexpr (WB) {
        return *(const bf8*)(Wb + WOFF[t] + hoff + vo + cc);
      } else {
        const float* base = (t < 2) ? Wqf : (t < 6) ? Wkvf : (t < 8) ? Wscf : Wshf;
        return ld_cvt8(base + (size_t)(h * 32 + ROWADD[t] + l15) * CH + quad * 8 + cc);
      }
    };

    // ===== Phase A: q,k,v,scale,shift N=160 GEMM, per-mt (16 rows) =====
    #pragma unroll
    for (int mt = 0; mt < 2; ++mt) {
      f4 acc[10];
      #pragma unroll
      for (int t = 0; t < 10; ++t) acc[t] = 0.0f;

      const float* xrow = x   + gbase + (size_t)(ib + 16 * mt + l15) * CH + quad * 8;
      const float* crow = ctx + gbase + (size_t)(ib + 16 * mt + l15) * CH + quad * 8;

      #pragma unroll
      for (int kc = 0; kc < 8; ++kc) {
        const int cc = kc * 32;
        bf8 ax = ld_cvt8(xrow + cc);
        bf8 ac = ld_cvt8(crow + cc);
        #pragma unroll
        for (int t = 0; t < 10; ++t)
          acc[t] = MFMA((t < 6) ? ax : ac, ldb(t, cc), acc[t]);
      }

      // FiLM modulation fully in-lane, write LDS
      #pragma unroll
      for (int r = 0; r < 4; ++r) {
        const int i = ib + 16 * mt + 4 * quad + r;
        const float sc0 = acc[6][r], sc1 = acc[7][r];
        const float sh0 = acc[8][r], sh1 = acc[9][r];
        sQ[i][l15]      = f2bf(sc0 * acc[0][r] + sh0);
        sQ[i][16 + l15] = f2bf(sc1 * acc[1][r] + sh1);
        sK[i][l15]      = f2bf(sc0 * acc[2][r] + sh0);
        sK[i][16 + l15] = f2bf(sc1 * acc[3][r] + sh1);
        sVT[l15][i]      = f2bf(sc0 * acc[4][r] + sh0);
        sVT[16 + l15][i] = f2bf(sc1 * acc[5][r] + sh1);
      }
    }
    __syncthreads();   // K,V from all waves visible

    // ===== per-mt: S = Q@K^T, softmax in regs, PV in 4 key-quarters =====
    #pragma unroll
    for (int mt = 0; mt < 2; ++mt) {
      const int i0 = ib + 16 * mt;
      bf8 aq = *(const bf8*)(&sQ[i0 + l15][quad * 8]);
      f4 sc[8];
      #pragma unroll
      for (int ct = 0; ct < 8; ++ct) {
        bf8 bk = *(const bf8*)(&sK[ct * 16 + l15][quad * 8]);
        f4 z = 0.0f;
        sc[ct] = MFMA(aq, bk, z);
      }

      float mx[4] = {-3.4e38f, -3.4e38f, -3.4e38f, -3.4e38f};
      #pragma unroll
      for (int ct = 0; ct < 8; ++ct)
        #pragma unroll
        for (int r = 0; r < 4; ++r) mx[r] = fmaxf(mx[r], sc[ct][r]);
      #pragma unroll
      for (int m = 1; m <= 8; m <<= 1)
        #pragma unroll
        for (int r = 0; r < 4; ++r) mx[r] = fmaxf(mx[r], __shfl_xor(mx[r], m));

      float sm[4] = {0.f, 0.f, 0.f, 0.f};
      #pragma unroll
      for (int ct = 0; ct < 8; ++ct)
        #pragma unroll
        for (int r = 0; r < 4; ++r) {
          float p = __expf((sc[ct][r] - mx[r]) * SCALE);
          sm[r] += p;
          sc[ct][r] = p;
        }
      #pragma unroll
      for (int m = 1; m <= 8; m <<= 1)
        #pragma unroll
        for (int r = 0; r < 4; ++r) sm[r] += __shfl_xor(sm[r], m);
      float rv[4];
      #pragma unroll
      for (int r = 0; r < 4; ++r) rv[r] = 1.0f / sm[r];

      // PV over 4 key-quarters through the small sP buffer (all wave-local,
      // in-order DS pipe + may-alias ordering keeps write->read->rewrite safe)
      f4 o0 = 0.0f, o1 = 0.0f;
      #pragma unroll
      for (int q = 0; q < 4; ++q) {
        #pragma unroll
        for (int c2 = 0; c2 < 2; ++c2) {
          const int ct = 2 * q + c2;
          #pragma unroll
          for (int r = 0; r < 4; ++r)
            sP[i0 + 4 * quad + r][c2 * 16 + l15] = f2bf(sc[ct][r]);
        }
        asm volatile("s_waitcnt lgkmcnt(0)" ::: "memory");
        bf8 ap  = *(const bf8*)(&sP[i0 + l15][quad * 8]);
        bf8 bv0 = *(const bf8*)(&sVT[l15][q * 32 + quad * 8]);
        bf8 bv1 = *(const bf8*)(&sVT[16 + l15][q * 32 + quad * 8]);
        o0 = MFMA(ap, bv0, o0);
        o1 = MFMA(ap, bv1, o1);
      }

      if constexpr (SPLIT) {
        // normalized O_h (bf16) straight to workspace
        #pragma unroll
        for (int r = 0; r < 4; ++r) {
          const size_t orow = gbase + (size_t)(i0 + 4 * quad + r) * CH + h * 32;
          Oh[orow + l15]      = f2bf(o0[r] * rv[r]);
          Oh[orow + 16 + l15] = f2bf(o1[r] * rv[r]);
        }
      } else {
        // stage O_h rows into sP cols 0..31 (wave-local; survives other mt)
        #pragma unroll
        for (int r = 0; r < 4; ++r) {
          sP[i0 + 4 * quad + r][l15]      = f2bf(o0[r] * rv[r]);
          sP[i0 + 4 * quad + r][16 + l15] = f2bf(o1[r] * rv[r]);
        }
      }
    }

    if constexpr (!SPLIT) {
      asm volatile("s_waitcnt lgkmcnt(0)" ::: "memory");
      bf8 a0 = *(const bf8*)(&sP[ib + l15][quad * 8]);
      bf8 a1 = *(const bf8*)(&sP[ib + 16 + l15][quad * 8]);
      #pragma unroll
      for (int nt = 0; nt < 16; ++nt) {
        bf8 b;
        if constexpr (WB) b = *(const bf8*)(Wb + OOUT + (size_t)(nt * 16 + l15) * CH + h * 32 + quad * 8);
        else              b = ld_cvt8(Woutf + (size_t)(nt * 16 + l15) * CH + h * 32 + quad * 8);
        pacc[0][nt] = MFMA(a0, b, pacc[0][nt]);
        pacc[1][nt] = MFMA(a1, b, pacc[1][nt]);
      }
    }
    __syncthreads();   // before next head overwrites sK/sVT (and sP/sQ)
  }

  if constexpr (!SPLIT) {
    #pragma unroll
    for (int mt = 0; mt < 2; ++mt)
      #pragma unroll
      for (int nt = 0; nt < 16; ++nt)
        #pragma unroll
        for (int r = 0; r < 4; ++r)
          out[gbase + (size_t)(ib + 16 * mt + 4 * quad + r) * CH + nt * 16 + l15] =
              pacc[mt][nt][r];
  }
}

// ===== kernel 2 (split mode): out = Oh @ Wout^T =====
__global__ __launch_bounds__(256, 2)
void proj_gemm(const u16* __restrict__ Oh, const u16* __restrict__ Wb,
               float* __restrict__ out)
{
  const int tid  = threadIdx.x;
  const int wave = tid >> 6;
  const int lane = tid & 63;
  const int l15  = lane & 15;
  const int quad = lane >> 4;
  const int g    = blockIdx.x;
  const size_t gbase = (size_t)g * (SEQ * CH);
  const int ib = wave * 32;

  f4 pacc[2][16];
  #pragma unroll
  for (int mt = 0; mt < 2; ++mt)
    #pragma unroll
    for (int nt = 0; nt < 16; ++nt) pacc[mt][nt] = 0.0f;

  const u16* arow = Oh + gbase + (size_t)(ib + l15) * CH + quad * 8;
  const u16* wrow = Wb + OOUT + (size_t)l15 * CH + quad * 8;

  #pragma unroll
  for (int kc = 0; kc < 8; ++kc) {
    const int cc = kc * 32;
    bf8 a0 = *(const bf8*)(arow + cc);
    bf8 a1 = *(const bf8*)(arow + 16 * CH + cc);
    #pragma unroll
    for (int nt = 0; nt < 16; ++nt) {
      bf8 b = *(const bf8*)(wrow + (size_t)nt * 16 * CH + cc);
      pacc[0][nt] = MFMA(a0, b, pacc[0][nt]);
      pacc[1][nt] = MFMA(a1, b, pacc[1][nt]);
    }
  }

  #pragma unroll
  for (int mt = 0; mt < 2; ++mt)
    #pragma unroll
    for (int nt = 0; nt < 16; ++nt)
      #pragma unroll
      for (int r = 0; r < 4; ++r)
        out[gbase + (size_t)(ib + 16 * mt + 4 * quad + r) * CH + nt * 16 + l15] =
            pacc[mt][nt][r];
}

extern "C" void kernel_launch(void* const* d_in, const int* in_sizes, int n_in,
                              void* d_out, int out_size, void* d_ws, size_t ws_size,
                              hipStream_t stream) {
  const float* x    = (const float*)d_in[0];
  const float* ctx  = (const float*)d_in[1];
  const float* Wq   = (const float*)d_in[2];
  const float* Wkv  = (const float*)d_in[3];
  const float* Wout = (const float*)d_in[4];
  const float* Wsc  = (const float*)d_in[5];
  const float* Wsh  = (const float*)d_in[6];
  float* o = (float*)d_out;

  const size_t need_w     = W_ELEMS * sizeof(u16);
  const size_t need_split = (W_ELEMS + OH_ELEMS) * sizeof(u16);   // ~67.9 MB

  if (ws_size >= need_split) {
    u16* w  = (u16*)d_ws;
    u16* oh = w + W_ELEMS;
    cvt_weights<<<dim3(192), dim3(256), 0, stream>>>(Wq, Wkv, Wout, Wsc, Wsh, w);
    fused_axattn<true, true><<<dim3(1024), dim3(256), 0, stream>>>(
        x, ctx, w, nullptr, nullptr, nullptr, nullptr, nullptr, oh, nullptr);
    proj_gemm<<<dim3(1024), dim3(256), 0, stream>>>(oh, w, o);
  } else if (ws_size >= need_w) {
    u16* w = (u16*)d_ws;
    cvt_weights<<<dim3(192), dim3(256), 0, stream>>>(Wq, Wkv, Wout, Wsc, Wsh, w);
    fused_axattn<true, false><<<dim3(1024), dim3(256), 0, stream>>>(
        x, ctx, w, nullptr, nullptr, nullptr, nullptr, nullptr, nullptr, o);
  } else {
    fused_axattn<false, false><<<dim3(1024), dim3(256), 0, stream>>>(
        x, ctx, nullptr, Wq, Wkv, Wsc, Wsh, Wout, nullptr, o);
  }
}

// Round 3
// 1013.697 us; speedup vs baseline: 1.2615x; 1.1078x over previous
//
#include <hip/hip_runtime.h>
#include <cstdint>

typedef short bf8 __attribute__((ext_vector_type(8)));   // 8 x bf16 (bit pattern)
typedef float f4  __attribute__((ext_vector_type(4)));
typedef uint32_t u32x4 __attribute__((ext_vector_type(4)));
typedef unsigned short u16;

__device__ __forceinline__ u16 f2bf(float f) {
  union { float f; uint32_t u; } v; v.f = f;
  uint32_t u = v.u + 0x7fffu + ((v.u >> 16) & 1u);   // RNE
  return (u16)(u >> 16);
}

__device__ __forceinline__ uint32_t pk2(float lo, float hi) {
  return (uint32_t)f2bf(lo) | ((uint32_t)f2bf(hi) << 16);
}

// load 8 consecutive f32 (16B-aligned) and convert to a bf16x8 MFMA fragment
__device__ __forceinline__ bf8 ld_cvt8(const float* p) {
  f4 a = *(const f4*)p;
  f4 b = *(const f4*)(p + 4);
  u32x4 r;
  r[0] = pk2(a[0], a[1]);
  r[1] = pk2(a[2], a[3]);
  r[2] = pk2(b[0], b[1]);
  r[3] = pk2(b[2], b[3]);
  return __builtin_bit_cast(bf8, r);
}

#define MFMA(a, b, c) __builtin_amdgcn_mfma_f32_16x16x32_bf16((a), (b), (c), 0, 0, 0)

// Problem constants: 1024 groups of (seq=128, C=256), 8 heads of e=32.
constexpr int SEQ = 128;
constexpr int CH  = 256;
constexpr int NH  = 8;
constexpr int NG  = 1024;

// bf16 weight workspace layout (u16 elems)
constexpr size_t OQ   = 0;
constexpr size_t OKV  = 65536;
constexpr size_t OOUT = 196608;
constexpr size_t OSC  = 262144;
constexpr size_t OSH  = 327680;
constexpr size_t W_ELEMS = 393216;
constexpr size_t XE      = (size_t)NG * SEQ * CH;   // 33,554,432 elems per activation buf

// weight-tile element offsets: q0,q1,k0,k1,v0,v1,sc0,sc1,sh0,sh1
__device__ constexpr size_t WOFF[10] = {
  OQ, OQ + 4096, OKV, OKV + 4096, OKV + 65536, OKV + 69632,
  OSC, OSC + 4096, OSH, OSH + 4096 };
__device__ constexpr int ROWADD[10] = {0, 16, 0, 16, 256, 272, 0, 16, 0, 16};

// ---- prepass: weights f32 -> bf16 workspace ----
__global__ void cvt_weights(const float* __restrict__ wq, const float* __restrict__ wkv,
                            const float* __restrict__ wout, const float* __restrict__ wsc,
                            const float* __restrict__ wsh, u16* __restrict__ dst) {
  int i = (blockIdx.x * 256 + threadIdx.x) * 8;   // 0 .. 393208
  const float* s; int off;
  if      (i <  65536) { s = wq;   off = i; }
  else if (i < 196608) { s = wkv;  off = i -  65536; }
  else if (i < 262144) { s = wout; off = i - 196608; }
  else if (i < 327680) { s = wsc;  off = i - 262144; }
  else                 { s = wsh;  off = i - 327680; }
  *(bf8*)(dst + i) = ld_cvt8(s + off);
}

// ================= stage 1: QKV + FiLM modulation ====================
// grid 2048 (= group * 2 row-halves), block 256 (4 waves), wave = 16 rows.
// A-fragments (x,ctx bf16) loaded ONCE into regs, reused for all 8 heads.
__global__ __launch_bounds__(256, 3)
void qkvmod(const float* __restrict__ x, const float* __restrict__ ctx,
            const u16* __restrict__ Wb,
            u16* __restrict__ Qm, u16* __restrict__ Km, u16* __restrict__ VmT)
{
  __shared__ u16 sVT[2][32][72];   // double-buffered local V^T stage: [d][local i]

  const int tid  = threadIdx.x;
  const int wave = tid >> 6;
  const int lane = tid & 63;
  const int l15  = lane & 15;
  const int quad = lane >> 4;
  const int g    = blockIdx.x >> 1;
  const int half = blockIdx.x & 1;
  const int i0   = half * 64 + wave * 16;          // wave's 16 rows (within group)
  const size_t gbase = (size_t)g * (SEQ * CH);
  const int vo = l15 * CH + quad * 8;              // per-lane weight offset (elems)

  // cache activation fragments for the whole kernel (64 VGPR)
  bf8 ax[8], ac[8];
  {
    const float* xr = x   + gbase + (size_t)(i0 + l15) * CH + quad * 8;
    const float* cr = ctx + gbase + (size_t)(i0 + l15) * CH + quad * 8;
    #pragma unroll
    for (int kc = 0; kc < 8; ++kc) { ax[kc] = ld_cvt8(xr + kc * 32); ac[kc] = ld_cvt8(cr + kc * 32); }
  }

  for (int h = 0; h < NH; ++h) {
    const int hoff = h * 32 * CH;
    f4 acc[10];
    #pragma unroll
    for (int t = 0; t < 10; ++t) acc[t] = 0.0f;

    #pragma unroll
    for (int kc = 0; kc < 8; ++kc) {
      const int cc = kc * 32;
      #pragma unroll
      for (int t = 0; t < 10; ++t) {
        bf8 b = *(const bf8*)(Wb + WOFF[t] + hoff + vo + cc);
        acc[t] = MFMA((t < 6) ? ax[kc] : ac[kc], b, acc[t]);
      }
    }

    // FiLM modulation; Q,K straight to global (row-major), V into LDS transpose stage
    #pragma unroll
    for (int r = 0; r < 4; ++r) {
      const int i  = i0 + 4 * quad + r;            // row within group
      const int il = i - half * 64;                // 0..63 local column of VT stage
      const float sc0 = acc[6][r], sc1 = acc[7][r];
      const float sh0 = acc[8][r], sh1 = acc[9][r];
      const size_t orow = gbase + (size_t)i * CH + h * 32;
      Qm[orow + l15]      = f2bf(sc0 * acc[0][r] + sh0);
      Qm[orow + 16 + l15] = f2bf(sc1 * acc[1][r] + sh1);
      Km[orow + l15]      = f2bf(sc0 * acc[2][r] + sh0);
      Km[orow + 16 + l15] = f2bf(sc1 * acc[3][r] + sh1);
      sVT[h & 1][l15][il]      = f2bf(sc0 * acc[4][r] + sh0);
      sVT[h & 1][16 + l15][il] = f2bf(sc1 * acc[5][r] + sh1);
    }
    __syncthreads();
    // coalesced dump: VmT[g*8+h][d][half*64 + 0..63]
    {
      const int d = tid >> 3, c8 = (tid & 7) * 8;  // 32 rows x 8 chunks of 8
      bf8 v = *(const bf8*)(&sVT[h & 1][d][c8]);
      *(bf8*)(VmT + ((size_t)(g * NH + h) * 32 + d) * SEQ + half * 64 + c8) = v;
    }
    // next head writes the other sVT buffer; its pre-dump barrier orders reuse
  }
}

// ================= stage 2: attention per (group, head) ====================
// grid 8192, block 256 (4 waves), wave = 32 Q-rows. Oh aliases Qm (safe: each
// block reads exactly the Q slice it later overwrites, data-dep ordered).
__global__ __launch_bounds__(256, 4)
void attn_heads(u16* Qm, const u16* __restrict__ Km, const u16* __restrict__ VmT)
{
  __shared__ u16 sK[SEQ][40];     // K head slice
  __shared__ u16 sVT[32][136];    // V^T head slice
  __shared__ u16 sP[SEQ][40];     // P quarter staging (wave-local rows)
  // LDS total = 10240 + 8704 + 10240 = 29184 B

  const int tid  = threadIdx.x;
  const int wave = tid >> 6;
  const int lane = tid & 63;
  const int l15  = lane & 15;
  const int quad = lane >> 4;
  const int g    = blockIdx.x >> 3;
  const int h    = blockIdx.x & 7;
  const size_t gbase = (size_t)g * (SEQ * CH);
  const int ib = wave * 32;

  const float SCALE = 0.17677669529663687f;  // 1/sqrt(32)

  // ---- stage K (128x32) and V^T (32x128) head slices into LDS ----
  #pragma unroll
  for (int it = 0; it < 2; ++it) {
    int idx = tid + it * 256;                 // 0..511
    int j = idx >> 2, c = (idx & 3) * 8;
    *(bf8*)(&sK[j][c]) = *(const bf8*)(Km + gbase + (size_t)j * CH + h * 32 + c);
  }
  #pragma unroll
  for (int it = 0; it < 2; ++it) {
    int idx = tid + it * 256;                 // 0..511
    int d = idx >> 4, c = (idx & 15) * 8;
    *(bf8*)(&sVT[d][c]) = *(const bf8*)(VmT + ((size_t)(g * NH + h) * 32 + d) * SEQ + c);
  }
  __syncthreads();

  // ---- per-mt: S = Q@K^T, softmax in regs, PV in 4 key-quarters ----
  #pragma unroll
  for (int mt = 0; mt < 2; ++mt) {
    const int i0 = ib + 16 * mt;
    bf8 aq = *(const bf8*)(Qm + gbase + (size_t)(i0 + l15) * CH + h * 32 + quad * 8);
    f4 sc[8];
    #pragma unroll
    for (int ct = 0; ct < 8; ++ct) {
      bf8 bk = *(const bf8*)(&sK[ct * 16 + l15][quad * 8]);
      f4 z = 0.0f;
      sc[ct] = MFMA(aq, bk, z);
    }

    float mx[4] = {-3.4e38f, -3.4e38f, -3.4e38f, -3.4e38f};
    #pragma unroll
    for (int ct = 0; ct < 8; ++ct)
      #pragma unroll
      for (int r = 0; r < 4; ++r) mx[r] = fmaxf(mx[r], sc[ct][r]);
    #pragma unroll
    for (int m = 1; m <= 8; m <<= 1)
      #pragma unroll
      for (int r = 0; r < 4; ++r) mx[r] = fmaxf(mx[r], __shfl_xor(mx[r], m));

    float sm[4] = {0.f, 0.f, 0.f, 0.f};
    #pragma unroll
    for (int ct = 0; ct < 8; ++ct)
      #pragma unroll
      for (int r = 0; r < 4; ++r) {
        float p = __expf((sc[ct][r] - mx[r]) * SCALE);
        sm[r] += p;
        sc[ct][r] = p;
      }
    #pragma unroll
    for (int m = 1; m <= 8; m <<= 1)
      #pragma unroll
      for (int r = 0; r < 4; ++r) sm[r] += __shfl_xor(sm[r], m);
    float rv[4];
    #pragma unroll
    for (int r = 0; r < 4; ++r) rv[r] = 1.0f / sm[r];

    // PV over 4 key-quarters through sP (wave-local rows; in-order DS pipe)
    f4 o0 = 0.0f, o1 = 0.0f;
    #pragma unroll
    for (int q = 0; q < 4; ++q) {
      #pragma unroll
      for (int c2 = 0; c2 < 2; ++c2) {
        const int ct = 2 * q + c2;
        #pragma unroll
        for (int r = 0; r < 4; ++r)
          sP[i0 + 4 * quad + r][c2 * 16 + l15] = f2bf(sc[ct][r]);
      }
      asm volatile("s_waitcnt lgkmcnt(0)" ::: "memory");
      bf8 ap  = *(const bf8*)(&sP[i0 + l15][quad * 8]);
      bf8 bv0 = *(const bf8*)(&sVT[l15][q * 32 + quad * 8]);
      bf8 bv1 = *(const bf8*)(&sVT[16 + l15][q * 32 + quad * 8]);
      o0 = MFMA(ap, bv0, o0);
      o1 = MFMA(ap, bv1, o1);
    }

    // normalized O_h (bf16) overwrites this block's own Q slice
    #pragma unroll
    for (int r = 0; r < 4; ++r) {
      const size_t orow = gbase + (size_t)(i0 + 4 * quad + r) * CH + h * 32;
      Qm[orow + l15]      = f2bf(o0[r] * rv[r]);
      Qm[orow + 16 + l15] = f2bf(o1[r] * rv[r]);
    }
  }
}

// ================= stage 3: out = Oh @ Wout^T ====================
__global__ __launch_bounds__(256, 2)
void proj_gemm(const u16* __restrict__ Oh, const u16* __restrict__ Wb,
               float* __restrict__ out)
{
  const int tid  = threadIdx.x;
  const int wave = tid >> 6;
  const int lane = tid & 63;
  const int l15  = lane & 15;
  const int quad = lane >> 4;
  const int g    = blockIdx.x;
  const size_t gbase = (size_t)g * (SEQ * CH);
  const int ib = wave * 32;

  f4 pacc[2][16];
  #pragma unroll
  for (int mt = 0; mt < 2; ++mt)
    #pragma unroll
    for (int nt = 0; nt < 16; ++nt) pacc[mt][nt] = 0.0f;

  const u16* arow = Oh + gbase + (size_t)(ib + l15) * CH + quad * 8;
  const u16* wrow = Wb + OOUT + (size_t)l15 * CH + quad * 8;

  #pragma unroll
  for (int kc = 0; kc < 8; ++kc) {
    const int cc = kc * 32;
    bf8 a0 = *(const bf8*)(arow + cc);
    bf8 a1 = *(const bf8*)(arow + 16 * CH + cc);
    #pragma unroll
    for (int nt = 0; nt < 16; ++nt) {
      bf8 b = *(const bf8*)(wrow + (size_t)nt * 16 * CH + cc);
      pacc[0][nt] = MFMA(a0, b, pacc[0][nt]);
      pacc[1][nt] = MFMA(a1, b, pacc[1][nt]);
    }
  }

  #pragma unroll
  for (int mt = 0; mt < 2; ++mt)
    #pragma unroll
    for (int nt = 0; nt < 16; ++nt)
      #pragma unroll
      for (int r = 0; r < 4; ++r)
        out[gbase + (size_t)(ib + 16 * mt + 4 * quad + r) * CH + nt * 16 + l15] =
            pacc[mt][nt][r];
}

// ================= fallback: fused single-kernel path (round-2, non-split) ====
template<bool WB>
__global__ __launch_bounds__(256, 2)
void fused_axattn(const float* __restrict__ x,   const float* __restrict__ ctx,
                  const u16* __restrict__ Wb,
                  const float* __restrict__ Wqf, const float* __restrict__ Wkvf,
                  const float* __restrict__ Wscf, const float* __restrict__ Wshf,
                  const float* __restrict__ Woutf, float* __restrict__ out)
{
  __shared__ u16 sQ[SEQ][40];
  __shared__ u16 sK[SEQ][40];
  __shared__ u16 sVT[32][136];
  __shared__ u16 sP[SEQ][40];

  const int tid  = threadIdx.x;
  const int wave = tid >> 6;
  const int lane = tid & 63;
  const int l15  = lane & 15;
  const int quad = lane >> 4;
  const int g    = blockIdx.x;
  const size_t gbase = (size_t)g * (SEQ * CH);
  const int ib = wave * 32;

  const float SCALE = 0.17677669529663687f;
  const int vo = l15 * CH + quad * 8;

  f4 pacc[2][16];
  #pragma unroll
  for (int mt = 0; mt < 2; ++mt)
    #pragma unroll
    for (int nt = 0; nt < 16; ++nt) pacc[mt][nt] = 0.0f;

  for (int h = 0; h < NH; ++h) {
    const int hoff = h * 32 * CH;
    auto ldb = [&](int t, int cc) -> bf8 {
      if constexpr (WB) {
        return *(const bf8*)(Wb + WOFF[t] + hoff + vo + cc);
      } else {
        const float* base = (t < 2) ? Wqf : (t < 6) ? Wkvf : (t < 8) ? Wscf : Wshf;
        return ld_cvt8(base + (size_t)(h * 32 + ROWADD[t] + l15) * CH + quad * 8 + cc);
      }
    };

    #pragma unroll
    for (int mt = 0; mt < 2; ++mt) {
      f4 acc[10];
      #pragma unroll
      for (int t = 0; t < 10; ++t) acc[t] = 0.0f;
      const float* xrow = x   + gbase + (size_t)(ib + 16 * mt + l15) * CH + quad * 8;
      const float* crow = ctx + gbase + (size_t)(ib + 16 * mt + l15) * CH + quad * 8;
      #pragma unroll
      for (int kc = 0; kc < 8; ++kc) {
        const int cc = kc * 32;
        bf8 axx = ld_cvt8(xrow + cc);
        bf8 acc2 = ld_cvt8(crow + cc);
        #pragma unroll
        for (int t = 0; t < 10; ++t)
          acc[t] = MFMA((t < 6) ? axx : acc2, ldb(t, cc), acc[t]);
      }
      #pragma unroll
      for (int r = 0; r < 4; ++r) {
        const int i = ib + 16 * mt + 4 * quad + r;
        const float sc0 = acc[6][r], sc1 = acc[7][r];
        const float sh0 = acc[8][r], sh1 = acc[9][r];
        sQ[i][l15]      = f2bf(sc0 * acc[0][r] + sh0);
        sQ[i][16 + l15] = f2bf(sc1 * acc[1][r] + sh1);
        sK[i][l15]      = f2bf(sc0 * acc[2][r] + sh0);
        sK[i][16 + l15] = f2bf(sc1 * acc[3][r] + sh1);
        sVT[l15][i]      = f2bf(sc0 * acc[4][r] + sh0);
        sVT[16 + l15][i] = f2bf(sc1 * acc[5][r] + sh1);
      }
    }
    __syncthreads();

    #pragma unroll
    for (int mt = 0; mt < 2; ++mt) {
      const int i0 = ib + 16 * mt;
      bf8 aq = *(const bf8*)(&sQ[i0 + l15][quad * 8]);
      f4 sc[8];
      #pragma unroll
      for (int ct = 0; ct < 8; ++ct) {
        bf8 bk = *(const bf8*)(&sK[ct * 16 + l15][quad * 8]);
        f4 z = 0.0f;
        sc[ct] = MFMA(aq, bk, z);
      }
      float mx[4] = {-3.4e38f, -3.4e38f, -3.4e38f, -3.4e38f};
      #pragma unroll
      for (int ct = 0; ct < 8; ++ct)
        #pragma unroll
        for (int r = 0; r < 4; ++r) mx[r] = fmaxf(mx[r], sc[ct][r]);
      #pragma unroll
      for (int m = 1; m <= 8; m <<= 1)
        #pragma unroll
        for (int r = 0; r < 4; ++r) mx[r] = fmaxf(mx[r], __shfl_xor(mx[r], m));
      float sm[4] = {0.f, 0.f, 0.f, 0.f};
      #pragma unroll
      for (int ct = 0; ct < 8; ++ct)
        #pragma unroll
        for (int r = 0; r < 4; ++r) {
          float p = __expf((sc[ct][r] - mx[r]) * SCALE);
          sm[r] += p;
          sc[ct][r] = p;
        }
      #pragma unroll
      for (int m = 1; m <= 8; m <<= 1)
        #pragma unroll
        for (int r = 0; r < 4; ++r) sm[r] += __shfl_xor(sm[r], m);
      float rv[4];
      #pragma unroll
      for (int r = 0; r < 4; ++r) rv[r] = 1.0f / sm[r];

      f4 o0 = 0.0f, o1 = 0.0f;
      #pragma unroll
      for (int q = 0; q < 4; ++q) {
        #pragma unroll
        for (int c2 = 0; c2 < 2; ++c2) {
          const int ct = 2 * q + c2;
          #pragma unroll
          for (int r = 0; r < 4; ++r)
            sP[i0 + 4 * quad + r][c2 * 16 + l15] = f2bf(sc[ct][r]);
        }
        asm volatile("s_waitcnt lgkmcnt(0)" ::: "memory");
        bf8 ap  = *(const bf8*)(&sP[i0 + l15][quad * 8]);
        bf8 bv0 = *(const bf8*)(&sVT[l15][q * 32 + quad * 8]);
        bf8 bv1 = *(const bf8*)(&sVT[16 + l15][q * 32 + quad * 8]);
        o0 = MFMA(ap, bv0, o0);
        o1 = MFMA(ap, bv1, o1);
      }
      #pragma unroll
      for (int r = 0; r < 4; ++r) {
        sP[i0 + 4 * quad + r][l15]      = f2bf(o0[r] * rv[r]);
        sP[i0 + 4 * quad + r][16 + l15] = f2bf(o1[r] * rv[r]);
      }
    }

    asm volatile("s_waitcnt lgkmcnt(0)" ::: "memory");
    {
      bf8 a0 = *(const bf8*)(&sP[ib + l15][quad * 8]);
      bf8 a1 = *(const bf8*)(&sP[ib + 16 + l15][quad * 8]);
      #pragma unroll
      for (int nt = 0; nt < 16; ++nt) {
        bf8 b;
        if constexpr (WB) b = *(const bf8*)(Wb + OOUT + (size_t)(nt * 16 + l15) * CH + h * 32 + quad * 8);
        else              b = ld_cvt8(Woutf + (size_t)(nt * 16 + l15) * CH + h * 32 + quad * 8);
        pacc[0][nt] = MFMA(a0, b, pacc[0][nt]);
        pacc[1][nt] = MFMA(a1, b, pacc[1][nt]);
      }
    }
    __syncthreads();
  }

  #pragma unroll
  for (int mt = 0; mt < 2; ++mt)
    #pragma unroll
    for (int nt = 0; nt < 16; ++nt)
      #pragma unroll
      for (int r = 0; r < 4; ++r)
        out[gbase + (size_t)(ib + 16 * mt + 4 * quad + r) * CH + nt * 16 + l15] =
            pacc[mt][nt][r];
}

extern "C" void kernel_launch(void* const* d_in, const int* in_sizes, int n_in,
                              void* d_out, int out_size, void* d_ws, size_t ws_size,
                              hipStream_t stream) {
  const float* x    = (const float*)d_in[0];
  const float* ctx  = (const float*)d_in[1];
  const float* Wq   = (const float*)d_in[2];
  const float* Wkv  = (const float*)d_in[3];
  const float* Wout = (const float*)d_in[4];
  const float* Wsc  = (const float*)d_in[5];
  const float* Wsh  = (const float*)d_in[6];
  float* o = (float*)d_out;

  const size_t need_w    = W_ELEMS * sizeof(u16);
  const size_t need_pipe = (W_ELEMS + 3 * XE) * sizeof(u16);   // ~202 MB

  if (ws_size >= need_pipe) {
    u16* w   = (u16*)d_ws;
    u16* qm  = w + W_ELEMS;       // 64 MB, later aliased by Oh
    u16* km  = qm + XE;
    u16* vmt = km + XE;
    cvt_weights<<<dim3(192), dim3(256), 0, stream>>>(Wq, Wkv, Wout, Wsc, Wsh, w);
    qkvmod<<<dim3(2048), dim3(256), 0, stream>>>(x, ctx, w, qm, km, vmt);
    attn_heads<<<dim3(8192), dim3(256), 0, stream>>>(qm, km, vmt);
    proj_gemm<<<dim3(1024), dim3(256), 0, stream>>>(qm, w, o);
  } else if (ws_size >= need_w) {
    u16* w = (u16*)d_ws;
    cvt_weights<<<dim3(192), dim3(256), 0, stream>>>(Wq, Wkv, Wout, Wsc, Wsh, w);
    fused_axattn<true><<<dim3(1024), dim3(256), 0, stream>>>(
        x, ctx, w, nullptr, nullptr, nullptr, nullptr, nullptr, o);
  } else {
    fused_axattn<false><<<dim3(1024), dim3(256), 0, stream>>>(
        x, ctx, nullptr, Wq, Wkv, Wsc, Wsh, Wout, o);
  }
}